// Round 5
// baseline (26.916 us; speedup 1.0000x reference)
//
#include <hip/hip_runtime.h>
#include <math.h>

// LSQ 2-bit weight quantizer, forward only.
// out[0 .. C*N)          = hard-quantized w_q  (nearest of 9 levels)
// out[C*N .. C*N+C)      = sH_s forward
// out[C*N+C .. C*N+2C)   = sL_s forward
//
// argmin tie-break = first occurrence in COEFFS order: compute true min m
// (tree min; value independent of associativity), then scan k = 8..0
// overwriting when d_k == m so the earliest k wins. Identical to the
// sequential strict-< scan, including exact-tie cases.
//
// Launch shape: persistent single-generation grid — 2048 blocks x 256
// threads = 8192 waves = 32 waves/CU, ALL co-resident. Each block handles
// C/2048 channels via grid-stride. Avoids the 4-generation drain tail of
// the previous 4096x512 launch.

typedef float f4 __attribute__((ext_vector_type(4)));

__device__ __forceinline__ float quant1(float xe, const float lv[9]) {
  float d0 = fabsf(xe - lv[0]);
  float d1 = fabsf(xe - lv[1]);
  float d2 = fabsf(xe - lv[2]);
  float d3 = fabsf(xe - lv[3]);
  float d4 = fabsf(xe);            // lv[4] == 0
  float d5 = fabsf(xe - lv[5]);
  float d6 = fabsf(xe - lv[6]);
  float d7 = fabsf(xe - lv[7]);
  float d8 = fabsf(xe - lv[8]);
  // min-tree shaped for v_min3_f32
  float m = fminf(fminf(fminf(fminf(d0, d1), d2),
                        fminf(fminf(d3, d4), d5)),
                  fminf(fminf(d6, d7), d8));
  float r = lv[8];
  r = (d7 == m) ? lv[7] : r;
  r = (d6 == m) ? lv[6] : r;
  r = (d5 == m) ? lv[5] : r;
  r = (d4 == m) ? lv[4] : r;
  r = (d3 == m) ? lv[3] : r;
  r = (d2 == m) ? lv[2] : r;
  r = (d1 == m) ? lv[1] : r;
  r = (d0 == m) ? lv[0] : r;
  return r;
}

__device__ __forceinline__ f4 quant4(f4 v, const float lv[9]) {
  f4 r;
  r.x = quant1(v.x, lv);
  r.y = quant1(v.y, lv);
  r.z = quant1(v.z, lv);
  r.w = quant1(v.w, lv);
  return r;
}

__global__ __launch_bounds__(256) void lsq2b_kernel(
    const float* __restrict__ x,
    const float* __restrict__ sH,
    const float* __restrict__ sL,
    float* __restrict__ out,
    int N, int C, float g, int nblocks) {
  const int bd = blockDim.x;
  const int nv = N >> 2;

  for (int c = blockIdx.x; c < C; c += nblocks) {
    const float sHv = sH[c];
    const float sLv = sL[c];
    const float tH = sHv * g;
    const float sH_s = (sHv - tH) + tH;
    const float tL = sLv * g;
    const float sL_s = (sLv - tL) + tL;

    float lv[9];
    lv[0] = -sH_s - sL_s;
    lv[1] = -sH_s;
    lv[2] = -sH_s + sL_s;
    lv[3] = -sL_s;
    lv[4] = 0.0f;
    lv[5] = sL_s;
    lv[6] = sH_s - sL_s;
    lv[7] = sH_s;
    lv[8] = sH_s + sL_s;

    const size_t row = (size_t)c * (size_t)N;
    const f4* __restrict__ xr = (const f4*)(x + row);
    f4* __restrict__ orow = (f4*)(out + row);

    if ((nv & (4 * bd - 1)) == 0) {
      // 4 f4 per thread per channel: all loads in flight, store as computed
      for (int base = 0; base < nv; base += 4 * bd) {
        const int i0 = base + threadIdx.x;
        f4 v0 = xr[i0];
        f4 v1 = xr[i0 + bd];
        f4 v2 = xr[i0 + 2 * bd];
        f4 v3 = xr[i0 + 3 * bd];
        f4 r0 = quant4(v0, lv);
        __builtin_nontemporal_store(r0, orow + i0);
        f4 r1 = quant4(v1, lv);
        __builtin_nontemporal_store(r1, orow + i0 + bd);
        f4 r2 = quant4(v2, lv);
        __builtin_nontemporal_store(r2, orow + i0 + 2 * bd);
        f4 r3 = quant4(v3, lv);
        __builtin_nontemporal_store(r3, orow + i0 + 3 * bd);
      }
    } else {
      for (int i = threadIdx.x; i < nv; i += bd) {
        f4 r = quant4(xr[i], lv);
        orow[i] = r;
      }
      for (int i = (nv << 2) + threadIdx.x; i < N; i += bd) {
        out[row + i] = quant1(x[row + i], lv);
      }
    }

    if (threadIdx.x == 0) {
      const size_t base = (size_t)C * (size_t)N;
      out[base + c] = sH_s;
      out[base + C + c] = sL_s;
    }
  }
}

extern "C" void kernel_launch(void* const* d_in, const int* in_sizes, int n_in,
                              void* d_out, int out_size, void* d_ws, size_t ws_size,
                              hipStream_t stream) {
  const float* x = (const float*)d_in[0];
  const float* sH = (const float*)d_in[1];
  const float* sL = (const float*)d_in[2];
  float* out = (float*)d_out;

  const int C = in_sizes[1];             // 4096 channels
  const int N = in_sizes[0] / C;         // 4096 per channel
  const float g = (float)(1.0 / sqrt(3.0 * (double)N));

  int nblocks = C < 2048 ? C : 2048;     // single co-resident generation
  lsq2b_kernel<<<nblocks, 256, 0, stream>>>(x, sH, sL, out, N, C, g, nblocks);
}

// Round 6
// 25.874 us; speedup vs baseline: 1.0403x; 1.0403x over previous
//
#include <hip/hip_runtime.h>
#include <math.h>

// LSQ 2-bit weight quantizer, forward only.  (Best-measured config: R4 —
// 4096 blocks x 512 threads, 2-deep ILP, plain loads + nontemporal stores.)
//
// out[0 .. C*N)          = hard-quantized w_q  (nearest of 9 levels)
// out[C*N .. C*N+C)      = sH_s forward
// out[C*N+C .. C*N+2C)   = sL_s forward
//
// argmin tie-break = first occurrence in COEFFS order: compute true min m
// (tree min; value independent of associativity), then scan k = 8..0
// overwriting when d_k == m so the earliest k wins. Identical to the
// sequential strict-< scan, including exact-tie cases (absmax 0.0 measured).
//
// Roofline note: 134.2 MB irreducible f32 traffic / 6.29 TB/s measured
// copy ceiling = 21.3 us hardware floor; dur_us additionally carries
// ~2-4 us graph-replay launch overhead. Five structurally-diverse
// variants (ILP 1/2/4-deep, nt on/off, 256/512 thd, persistent grid)
// all measured 25.9-26.9 us -> at the mixed-stream memory limit.

typedef float f4 __attribute__((ext_vector_type(4)));

__device__ __forceinline__ float quant1(float xe, const float lv[9]) {
  float d0 = fabsf(xe - lv[0]);
  float d1 = fabsf(xe - lv[1]);
  float d2 = fabsf(xe - lv[2]);
  float d3 = fabsf(xe - lv[3]);
  float d4 = fabsf(xe);            // lv[4] == 0
  float d5 = fabsf(xe - lv[5]);
  float d6 = fabsf(xe - lv[6]);
  float d7 = fabsf(xe - lv[7]);
  float d8 = fabsf(xe - lv[8]);
  // min-tree shaped for v_min3_f32
  float m = fminf(fminf(fminf(fminf(d0, d1), d2),
                        fminf(fminf(d3, d4), d5)),
                  fminf(fminf(d6, d7), d8));
  float r = lv[8];
  r = (d7 == m) ? lv[7] : r;
  r = (d6 == m) ? lv[6] : r;
  r = (d5 == m) ? lv[5] : r;
  r = (d4 == m) ? lv[4] : r;
  r = (d3 == m) ? lv[3] : r;
  r = (d2 == m) ? lv[2] : r;
  r = (d1 == m) ? lv[1] : r;
  r = (d0 == m) ? lv[0] : r;
  return r;
}

__device__ __forceinline__ f4 quant4(f4 v, const float lv[9]) {
  f4 r;
  r.x = quant1(v.x, lv);
  r.y = quant1(v.y, lv);
  r.z = quant1(v.z, lv);
  r.w = quant1(v.w, lv);
  return r;
}

__global__ __launch_bounds__(512) void lsq2b_kernel(
    const float* __restrict__ x,
    const float* __restrict__ sH,
    const float* __restrict__ sL,
    float* __restrict__ out,
    int N, int C, float g) {
  const int c = blockIdx.x;

  const float sHv = sH[c];
  const float sLv = sL[c];
  const float tH = sHv * g;
  const float sH_s = (sHv - tH) + tH;
  const float tL = sLv * g;
  const float sL_s = (sLv - tL) + tL;

  float lv[9];
  lv[0] = -sH_s - sL_s;
  lv[1] = -sH_s;
  lv[2] = -sH_s + sL_s;
  lv[3] = -sL_s;
  lv[4] = 0.0f;
  lv[5] = sL_s;
  lv[6] = sH_s - sL_s;
  lv[7] = sH_s;
  lv[8] = sH_s + sL_s;

  const size_t row = (size_t)c * (size_t)N;
  const f4* __restrict__ xr = (const f4*)(x + row);
  f4* __restrict__ orow = (f4*)(out + row);
  const int nv = N >> 2;
  const int bd = blockDim.x;

  if ((nv & (2 * bd - 1)) == 0) {
    // 2-deep: both loads in flight, store each result as soon as computed
    for (int base = 0; base < nv; base += 2 * bd) {
      const int i0 = base + threadIdx.x;
      f4 v0 = xr[i0];
      f4 v1 = xr[i0 + bd];
      f4 r0 = quant4(v0, lv);
      __builtin_nontemporal_store(r0, orow + i0);
      f4 r1 = quant4(v1, lv);
      __builtin_nontemporal_store(r1, orow + i0 + bd);
    }
  } else {
    for (int i = threadIdx.x; i < nv; i += bd) {
      f4 r = quant4(xr[i], lv);
      orow[i] = r;
    }
    for (int i = (nv << 2) + threadIdx.x; i < N; i += bd) {
      out[row + i] = quant1(x[row + i], lv);
    }
  }

  if (threadIdx.x == 0) {
    const size_t base = (size_t)C * (size_t)N;
    out[base + c] = sH_s;
    out[base + C + c] = sL_s;
  }
}

extern "C" void kernel_launch(void* const* d_in, const int* in_sizes, int n_in,
                              void* d_out, int out_size, void* d_ws, size_t ws_size,
                              hipStream_t stream) {
  const float* x = (const float*)d_in[0];
  const float* sH = (const float*)d_in[1];
  const float* sL = (const float*)d_in[2];
  float* out = (float*)d_out;

  const int C = in_sizes[1];             // 4096 channels
  const int N = in_sizes[0] / C;         // 4096 per channel
  const float g = (float)(1.0 / sqrt(3.0 * (double)N));

  lsq2b_kernel<<<C, 512, 0, stream>>>(x, sH, sL, out, N, C, g);
}